// Round 2
// baseline (465.443 us; speedup 1.0000x reference)
//
#include <hip/hip_runtime.h>

// Problem constants (B,C,H,W) = (4,64,512,512), labels in [0,1024)
#define NB 4
#define NC 64
#define HW (512*512)
#define NSEG 1024
#define BK (NB*NSEG)          // 4096 segments total
#define CG 16                 // channels per group
#define NCG (NC/CG)           // 4 channel groups

// k_accum geometry: 256 blocks (1/CU), each owns 16384 pixels of one (b,cg)
#define ACHUNKS 16
#define ACHUNK_PIX (HW/ACHUNKS)   // 16384 = 4 iters * 1024 thr * 4 px
// k_apply geometry: 512 blocks, each owns 8192 pixels of one (b,cg)
#define PCHUNKS 32
#define PCHUNK_PIX (HW/PCHUNKS)   // 8192 = 2 iters * 1024 thr * 4 px

// workspace layout in 32-bit words
#define OFF_SUMS   0                  // float[BK*NC]   = 262144
#define OFF_CNT    (BK*NC)            // int[BK]        = 4096
#define OFF_MAX    (OFF_CNT + BK)     // int[1]
#define ZERO_WORDS (OFF_MAX + 1)
#define OFF_SCALED 270336             // float[BK*NC]

#define WEIGHT 0.1f
#define EPSV   1e-5f

__global__ void k_zero(unsigned int* __restrict__ ws) {
    int i = blockIdx.x * blockDim.x + threadIdx.x;
    int stride = gridDim.x * blockDim.x;
    for (; i < ZERO_WORDS; i += stride) ws[i] = 0u;
}

// Per-block label histogram + max. grid = NB*128 blocks of 256 threads.
__global__ void k_hist(const int* __restrict__ sup, int* __restrict__ ws) {
    __shared__ int hist[NSEG];
    __shared__ int bmax;
    const int tid = threadIdx.x;
    for (int i = tid; i < NSEG; i += 256) hist[i] = 0;
    if (tid == 0) bmax = 0;
    __syncthreads();

    const int bid   = blockIdx.x;
    const int b     = bid >> 7;
    const int chunk = bid & 127;
    const int4* base = (const int4*)(sup + (size_t)b * HW + chunk * 2048);

    int lmax = 0;
    #pragma unroll
    for (int it = 0; it < 2; ++it) {
        int4 l4 = base[it * 256 + tid];
        atomicAdd(&hist[l4.x], 1);
        atomicAdd(&hist[l4.y], 1);
        atomicAdd(&hist[l4.z], 1);
        atomicAdd(&hist[l4.w], 1);
        lmax = max(lmax, max(max(l4.x, l4.y), max(l4.z, l4.w)));
    }
    atomicMax(&bmax, lmax);
    __syncthreads();

    int* counts = ws + OFF_CNT;
    for (int i = tid; i < NSEG; i += 256) {
        int h = hist[i];
        if (h) atomicAdd(&counts[b * NSEG + i], h);
    }
    if (tid == 0) atomicMax(&ws[OFF_MAX], bmax);
}

// --- k_accum helpers: statically-indexed batches of 8 float4 loads ---
#define ATOM4(Lv, cc, V) { \
    atomicAdd(&tbl[(Lv).x * CG + (((cc) + (Lv).x) & 15)], (V).x); \
    atomicAdd(&tbl[(Lv).y * CG + (((cc) + (Lv).y) & 15)], (V).y); \
    atomicAdd(&tbl[(Lv).z * CG + (((cc) + (Lv).z) & 15)], (V).z); \
    atomicAdd(&tbl[(Lv).w * CG + (((cc) + (Lv).w) & 15)], (V).w); }

#define LOADB(buf, it, half) { \
    _Pragma("unroll") \
    for (int c = 0; c < 8; ++c) \
        buf[c] = *(const float4*)(ib + (size_t)((half)*8 + c) * HW + (it)*4096); }

#define CONSB(buf, it, half) { \
    _Pragma("unroll") \
    for (int c = 0; c < 8; ++c) ATOM4(L[(it)], (half)*8 + c, buf[c]); }

// Segment-sum accumulation. grid = NB*NCG*ACHUNKS = 256 blocks of 1024.
// LDS table [NSEG][CG] fp32 = 64 KB, swizzled slot: l*CG + ((c+l)&15).
// Triple-buffered load pipeline keeps ~16-24 float4 loads in flight/wave.
__global__ __launch_bounds__(1024, 4)
void k_accum(const float* __restrict__ inp, const int* __restrict__ sup,
             float* __restrict__ ws) {
    __shared__ float tbl[NSEG * CG];
    const int tid = threadIdx.x;
    const int bid = blockIdx.x;
    const int chunk = bid & (ACHUNKS - 1);
    const int cgb   = bid >> 4;
    const int cg    = cgb & 3;
    const int b     = cgb >> 2;

    for (int i = tid; i < NSEG * CG; i += 1024) tbl[i] = 0.f;
    __syncthreads();

    const int pbase = chunk * ACHUNK_PIX;
    const int* supb = sup + (size_t)b * HW + pbase + tid * 4;
    const float* ib = inp + ((size_t)(b * NC + cg * CG)) * HW + pbase + tid * 4;

    int4 L[4];
    #pragma unroll
    for (int i = 0; i < 4; ++i) L[i] = *(const int4*)(supb + i * 4096);

    float4 va[8], vb[8], vc[8];
    LOADB(va, 0, 0); LOADB(vb, 0, 1); LOADB(vc, 1, 0);
    CONSB(va, 0, 0); LOADB(va, 1, 1);
    CONSB(vb, 0, 1); LOADB(vb, 2, 0);
    CONSB(vc, 1, 0); LOADB(vc, 2, 1);
    CONSB(va, 1, 1); LOADB(va, 3, 0);
    CONSB(vb, 2, 0); LOADB(vb, 3, 1);
    CONSB(vc, 2, 1);
    CONSB(va, 3, 0);
    CONSB(vb, 3, 1);

    __syncthreads();
    float* sums = ws + OFF_SUMS;
    for (int e = tid; e < NSEG * CG; e += 1024) {
        const int seg = e >> 4;
        const int j   = e & 15;
        const int c16 = (j - seg) & 15;
        const float v = tbl[e];
        if (v != 0.f)
            atomicAdd(&sums[((size_t)(b * NSEG + seg)) * NC + cg * CG + c16], v);
    }
}

// scaled[s*64+c] = (l < maxele) ? WEIGHT * sums / (cnt + EPS) : 0
__global__ void k_means(float* __restrict__ ws) {
    const int idx = blockIdx.x * 256 + threadIdx.x;   // < BK*NC
    const float* sums   = ws + OFF_SUMS;
    const int*   counts = (const int*)ws + OFF_CNT;
    const int    maxele = ((const int*)ws)[OFF_MAX];
    float* scaled = ws + OFF_SCALED;
    const int s = idx >> 6;
    const int l = s & (NSEG - 1);
    const float cnt = (float)counts[s];
    const float m = WEIGHT * sums[idx] / (cnt + EPSV);
    scaled[idx] = (l < maxele) ? m : 0.f;
}

// --- k_apply helpers ---
#define PLOAD(buf, it, half) { \
    _Pragma("unroll") \
    for (int c = 0; c < 8; ++c) \
        buf[c] = *(const float4*)(ib + (size_t)((half)*8 + c) * HW + (it)*4096); }

#define PCONS(buf, it, half) { \
    _Pragma("unroll") \
    for (int c = 0; c < 8; ++c) { \
        float4 v = buf[c]; \
        const int4 Lv = L[(it)]; \
        const int cc = (half)*8 + c; \
        v.x += tbl[Lv.x * CG + ((cc + Lv.x) & 15)]; \
        v.y += tbl[Lv.y * CG + ((cc + Lv.y) & 15)]; \
        v.z += tbl[Lv.z * CG + ((cc + Lv.z) & 15)]; \
        v.w += tbl[Lv.w * CG + ((cc + Lv.w) & 15)]; \
        *(float4*)(ob + (size_t)cc * HW + (it)*4096) = v; } }

// Apply: out = inp + scaled[seg][c]. grid = NB*NCG*PCHUNKS = 512 blocks.
__global__ __launch_bounds__(1024, 4)
void k_apply(const float* __restrict__ inp, const int* __restrict__ sup,
             const float* __restrict__ ws, float* __restrict__ out) {
    __shared__ float tbl[NSEG * CG];
    const int tid = threadIdx.x;
    const int bid = blockIdx.x;
    const int chunk = bid & (PCHUNKS - 1);
    const int cgb   = bid >> 5;
    const int cg    = cgb & 3;
    const int b     = cgb >> 2;

    const float* scaled = ws + OFF_SCALED;
    for (int e = tid; e < NSEG * CG; e += 1024) {
        const int seg = e >> 4;
        const int j   = e & 15;
        const int c16 = (j - seg) & 15;
        tbl[e] = scaled[((size_t)(b * NSEG + seg)) * NC + cg * CG + c16];
    }

    const int pbase = chunk * PCHUNK_PIX;
    const int* supb = sup + (size_t)b * HW + pbase + tid * 4;
    const float* ib = inp + ((size_t)(b * NC + cg * CG)) * HW + pbase + tid * 4;
    float* ob       = out + ((size_t)(b * NC + cg * CG)) * HW + pbase + tid * 4;

    int4 L[2];
    L[0] = *(const int4*)(supb);
    L[1] = *(const int4*)(supb + 4096);

    float4 va[8], vb[8];
    PLOAD(va, 0, 0); PLOAD(vb, 0, 1);
    __syncthreads();   // tbl staged (drains the early loads too — once per block)
    PCONS(va, 0, 0); PLOAD(va, 1, 0);
    PCONS(vb, 0, 1); PLOAD(vb, 1, 1);
    PCONS(va, 1, 0);
    PCONS(vb, 1, 1);
}

extern "C" void kernel_launch(void* const* d_in, const int* in_sizes, int n_in,
                              void* d_out, int out_size, void* d_ws, size_t ws_size,
                              hipStream_t stream) {
    const float* inp = (const float*)d_in[0];
    const int*   sup = (const int*)d_in[1];
    float* out = (float*)d_out;
    float* ws  = (float*)d_ws;

    k_zero<<<512, 256, 0, stream>>>((unsigned int*)d_ws);
    k_hist<<<NB * 128, 256, 0, stream>>>(sup, (int*)d_ws);
    k_accum<<<NB * NCG * ACHUNKS, 1024, 0, stream>>>(inp, sup, ws);
    k_means<<<(BK * NC) / 256, 256, 0, stream>>>(ws);
    k_apply<<<NB * NCG * PCHUNKS, 1024, 0, stream>>>(inp, sup, ws, out);
}

// Round 3
// 244.372 us; speedup vs baseline: 1.9047x; 1.9047x over previous
//
#include <hip/hip_runtime.h>

// Problem constants (B,C,H,W) = (4,64,512,512), labels in [0,1024)
#define NB 4
#define NC 64
#define HW (512*512)
#define NSEG 1024
#define BK (NB*NSEG)          // 4096 segments total
#define CG 16                 // channels per group
#define NCG (NC/CG)           // 4 channel groups

// k_accum geometry: 512 blocks of 512 thr, each owns 8192 px of one (b,cg)
#define ACHUNKS 32
#define ACHUNK_PIX (HW/ACHUNKS)   // 8192 = 4 iters * 512 thr * 4 px
// k_apply geometry: 512 blocks of 1024 thr, each owns 8192 px of one (b,cg)
#define PCHUNKS 32
#define PCHUNK_PIX (HW/PCHUNKS)

// fixed-point scales
#define SFT_LDS 12            // LDS accumulation at 2^12
#define SFT_GLB 10            // global accumulation at 2^10
#define SCALE_LDS 4096.0f
#define INV_GLB (1.0f/1024.0f)

// workspace layout in 32-bit words
#define OFF_SUMS   0                  // int[BK*NC] = 262144 (fixed-point 2^10)
#define OFF_CNT    (BK*NC)            // int[BK]    = 4096
#define OFF_MAX    (OFF_CNT + BK)     // int[1]
#define ZERO_WORDS (OFF_MAX + 1)
#define OFF_SCALED 270336             // float[BK*NC]

#define WEIGHT 0.1f
#define EPSV   1e-5f

__global__ void k_zero(unsigned int* __restrict__ ws) {
    int i = blockIdx.x * blockDim.x + threadIdx.x;
    int stride = gridDim.x * blockDim.x;
    for (; i < ZERO_WORDS; i += stride) ws[i] = 0u;
}

// Per-block label histogram + max. grid = NB*128 blocks of 256 threads.
__global__ void k_hist(const int* __restrict__ sup, int* __restrict__ ws) {
    __shared__ int hist[NSEG];
    __shared__ int bmax;
    const int tid = threadIdx.x;
    for (int i = tid; i < NSEG; i += 256) hist[i] = 0;
    if (tid == 0) bmax = 0;
    __syncthreads();

    const int bid   = blockIdx.x;
    const int b     = bid >> 7;
    const int chunk = bid & 127;
    const int4* base = (const int4*)(sup + (size_t)b * HW + chunk * 2048);

    int lmax = 0;
    #pragma unroll
    for (int it = 0; it < 2; ++it) {
        int4 l4 = base[it * 256 + tid];
        atomicAdd(&hist[l4.x], 1);
        atomicAdd(&hist[l4.y], 1);
        atomicAdd(&hist[l4.z], 1);
        atomicAdd(&hist[l4.w], 1);
        lmax = max(lmax, max(max(l4.x, l4.y), max(l4.z, l4.w)));
    }
    atomicMax(&bmax, lmax);
    __syncthreads();

    int* counts = ws + OFF_CNT;
    for (int i = tid; i < NSEG; i += 256) {
        int h = hist[i];
        if (h) atomicAdd(&counts[b * NSEG + i], h);
    }
    if (tid == 0) atomicMax(&ws[OFF_MAX], bmax);
}

__device__ __forceinline__ int f2fix(float x) {
    return (int)__builtin_rintf(x * SCALE_LDS);
}

// --- k_accum helpers ---
#define ATOM4I(Lv, cc, V) { \
    atomicAdd(&tbl[(Lv).x * CG + (((cc) + (Lv).x) & 15)], f2fix((V).x)); \
    atomicAdd(&tbl[(Lv).y * CG + (((cc) + (Lv).y) & 15)], f2fix((V).y)); \
    atomicAdd(&tbl[(Lv).z * CG + (((cc) + (Lv).z) & 15)], f2fix((V).z)); \
    atomicAdd(&tbl[(Lv).w * CG + (((cc) + (Lv).w) & 15)], f2fix((V).w)); }

#define LOADB(buf, it, half) { \
    _Pragma("unroll") \
    for (int c = 0; c < 8; ++c) \
        buf[c] = *(const float4*)(ib + (size_t)((half)*8 + c) * HW + (it)*2048); }

#define CONSB(buf, Lv, half) { \
    _Pragma("unroll") \
    for (int c = 0; c < 8; ++c) ATOM4I(Lv, (half)*8 + c, buf[c]); }

// Segment-sum accumulation, int fixed-point LDS table (native ds_add_u32).
// grid = NB*NCG*ACHUNKS = 512 blocks of 512 threads; 2 blocks/CU, 128KB LDS.
// Table [NSEG][CG] int, swizzled slot: l*CG + ((c+l)&15).
__global__ __launch_bounds__(512, 4)
void k_accum(const float* __restrict__ inp, const int* __restrict__ sup,
             int* __restrict__ ws) {
    __shared__ int tbl[NSEG * CG];
    const int tid = threadIdx.x;
    const int bid = blockIdx.x;
    const int chunk = bid & (ACHUNKS - 1);
    const int cgb   = bid >> 5;
    const int cg    = cgb & 3;
    const int b     = cgb >> 2;

    for (int i = tid; i < NSEG * CG; i += 512) tbl[i] = 0;
    __syncthreads();

    const int pbase = chunk * ACHUNK_PIX;
    const int4* sup4 = (const int4*)(sup + (size_t)b * HW + pbase) + tid;
    const float* ib  = inp + ((size_t)(b * NC + cg * CG)) * HW + pbase + tid * 4;

    const int4 L0 = sup4[0];
    const int4 L1 = sup4[512];
    const int4 L2 = sup4[1024];
    const int4 L3 = sup4[1536];

    float4 A[8], B[8];
    LOADB(A, 0, 0); LOADB(B, 0, 1);
    CONSB(A, L0, 0); LOADB(A, 1, 0);
    CONSB(B, L0, 1); LOADB(B, 1, 1);
    CONSB(A, L1, 0); LOADB(A, 2, 0);
    CONSB(B, L1, 1); LOADB(B, 2, 1);
    CONSB(A, L2, 0); LOADB(A, 3, 0);
    CONSB(B, L2, 1); LOADB(B, 3, 1);
    CONSB(A, L3, 0);
    CONSB(B, L3, 1);

    __syncthreads();
    int* sums = ws + OFF_SUMS;
    for (int e = tid; e < NSEG * CG; e += 512) {
        const int v = tbl[e];
        if (v) {
            const int seg = e >> 4;
            const int c16 = ((e & 15) - seg) & 15;
            const int g = (v + 2) >> 2;   // rescale 2^12 -> 2^10, ~round-nearest
            atomicAdd(&sums[((size_t)(b * NSEG + seg)) * NC + cg * CG + c16], g);
        }
    }
}

// scaled[s*64+c] = (l < maxele) ? WEIGHT * (sum*2^-10) / (cnt + EPS) : 0
__global__ void k_means(int* __restrict__ wsi, float* __restrict__ wsf) {
    const int idx = blockIdx.x * 256 + threadIdx.x;   // < BK*NC
    const int* sums   = wsi + OFF_SUMS;
    const int* counts = wsi + OFF_CNT;
    const int  maxele = wsi[OFF_MAX];
    float* scaled = wsf + OFF_SCALED;
    const int s = idx >> 6;
    const int l = s & (NSEG - 1);
    const float cnt = (float)counts[s];
    const float sumf = (float)sums[idx] * INV_GLB;
    const float m = WEIGHT * sumf / (cnt + EPSV);
    scaled[idx] = (l < maxele) ? m : 0.f;
}

// --- k_apply helpers ---
#define PLOAD(buf, it, half) { \
    _Pragma("unroll") \
    for (int c = 0; c < 8; ++c) \
        buf[c] = *(const float4*)(ib + (size_t)((half)*8 + c) * HW + (it)*4096); }

#define PCONS(buf, it, half) { \
    _Pragma("unroll") \
    for (int c = 0; c < 8; ++c) { \
        float4 v = buf[c]; \
        const int4 Lv = L[(it)]; \
        const int cc = (half)*8 + c; \
        v.x += tbl[Lv.x * CG + ((cc + Lv.x) & 15)]; \
        v.y += tbl[Lv.y * CG + ((cc + Lv.y) & 15)]; \
        v.z += tbl[Lv.z * CG + ((cc + Lv.z) & 15)]; \
        v.w += tbl[Lv.w * CG + ((cc + Lv.w) & 15)]; \
        *(float4*)(ob + (size_t)cc * HW + (it)*4096) = v; } }

// Apply: out = inp + scaled[seg][c]. grid = NB*NCG*PCHUNKS = 512 blocks.
__global__ __launch_bounds__(1024, 4)
void k_apply(const float* __restrict__ inp, const int* __restrict__ sup,
             const float* __restrict__ ws, float* __restrict__ out) {
    __shared__ float tbl[NSEG * CG];
    const int tid = threadIdx.x;
    const int bid = blockIdx.x;
    const int chunk = bid & (PCHUNKS - 1);
    const int cgb   = bid >> 5;
    const int cg    = cgb & 3;
    const int b     = cgb >> 2;

    const float* scaled = ws + OFF_SCALED;
    for (int e = tid; e < NSEG * CG; e += 1024) {
        const int seg = e >> 4;
        const int j   = e & 15;
        const int c16 = (j - seg) & 15;
        tbl[e] = scaled[((size_t)(b * NSEG + seg)) * NC + cg * CG + c16];
    }

    const int pbase = chunk * PCHUNK_PIX;
    const int* supb = sup + (size_t)b * HW + pbase + tid * 4;
    const float* ib = inp + ((size_t)(b * NC + cg * CG)) * HW + pbase + tid * 4;
    float* ob       = out + ((size_t)(b * NC + cg * CG)) * HW + pbase + tid * 4;

    int4 L[2];
    L[0] = *(const int4*)(supb);
    L[1] = *(const int4*)(supb + 4096);

    float4 va[8], vb[8];
    PLOAD(va, 0, 0); PLOAD(vb, 0, 1);
    __syncthreads();   // tbl staged
    PCONS(va, 0, 0); PLOAD(va, 1, 0);
    PCONS(vb, 0, 1); PLOAD(vb, 1, 1);
    PCONS(va, 1, 0);
    PCONS(vb, 1, 1);
}

extern "C" void kernel_launch(void* const* d_in, const int* in_sizes, int n_in,
                              void* d_out, int out_size, void* d_ws, size_t ws_size,
                              hipStream_t stream) {
    const float* inp = (const float*)d_in[0];
    const int*   sup = (const int*)d_in[1];
    float* out = (float*)d_out;

    k_zero<<<512, 256, 0, stream>>>((unsigned int*)d_ws);
    k_hist<<<NB * 128, 256, 0, stream>>>(sup, (int*)d_ws);
    k_accum<<<NB * NCG * ACHUNKS, 512, 0, stream>>>(inp, sup, (int*)d_ws);
    k_means<<<(BK * NC) / 256, 256, 0, stream>>>((int*)d_ws, (float*)d_ws);
    k_apply<<<NB * NCG * PCHUNKS, 1024, 0, stream>>>(inp, sup, (const float*)d_ws, out);
}